// Round 1
// baseline (304.601 us; speedup 1.0000x reference)
//
#include <hip/hip_runtime.h>
#include <hip/hip_bf16.h>

typedef short bf16x8 __attribute__((ext_vector_type(8)));
typedef float f32x4 __attribute__((ext_vector_type(4)));

__device__ __forceinline__ short f2bf(float f) {
    union { float f; unsigned u; } v; v.f = f;
    unsigned r = (v.u + 0x7FFFu + ((v.u >> 16) & 1u)) >> 16;
    return (short)r;
}

__device__ __forceinline__ float selu_f(float x) {
    const float scale = 1.0507009873554805f;
    const float sa = 1.0507009873554805f * 1.6732632423543772f;
    return x > 0.f ? scale * x : sa * (__expf(x) - 1.f);
}

// ---------------------------------------------------------------------------
// Kernel 1: gather-mean over trajectory cells + f2 MLP (selu), output bf16
// ---------------------------------------------------------------------------
__global__ void __launch_bounds__(256) prep_ctr_kernel(
    const float* __restrict__ c, const int* __restrict__ lat_idx,
    const int* __restrict__ lon_idx, const float* __restrict__ W1,
    const float* __restrict__ B1, const float* __restrict__ W2,
    const float* __restrict__ B2, short* __restrict__ ctr)
{
    __shared__ int cells[64];
    __shared__ float ctraj[128];
    __shared__ float hbuf[256];
    const int b = blockIdx.x;
    const int t = threadIdx.x;

    if (t < 64) cells[t] = lat_idx[b * 64 + t] * 17 + lon_idx[b * 64 + t];
    __syncthreads();

    if (t < 128) {
        float s = 0.f;
        #pragma unroll 8
        for (int j = 0; j < 64; ++j) s += c[t * 289 + cells[j]];
        ctraj[t] = s * (1.f / 64.f);
    }
    __syncthreads();

    {
        float acc = B1[t];
        #pragma unroll 8
        for (int i = 0; i < 128; ++i) acc += ctraj[i] * W1[i * 256 + t];
        hbuf[t] = selu_f(acc);
    }
    __syncthreads();

    if (t < 128) {
        float acc = B2[t];
        #pragma unroll 8
        for (int i = 0; i < 256; ++i) acc += hbuf[i] * W2[i * 128 + t];
        ctr[b * 128 + t] = f2bf(acc);
    }
}

// ---------------------------------------------------------------------------
// Kernel 2: transpose+cast f_W1 (384,512) f32 -> W1T (512,384) bf16
// ---------------------------------------------------------------------------
__global__ void __launch_bounds__(256) transpose_w1_kernel(
    const float* __restrict__ W1, short* __restrict__ w1t)
{
    int id = blockIdx.x * 256 + threadIdx.x;   // 0 .. 196607
    int n = id / 384;
    int k = id - n * 384;
    w1t[id] = f2bf(W1[k * 512 + n]);
}

// ---------------------------------------------------------------------------
// Kernel 3: fused GEMM (bf16 MFMA) + selu + W21/W22 row-dots
// grid = 512 b * 4 s-chunks; 256 threads = 4 waves (1x4 column split)
// ---------------------------------------------------------------------------
__global__ void __launch_bounds__(256) fused_gemm_kernel(
    const float* __restrict__ rho, const short* __restrict__ ctr,
    const short* __restrict__ w1t, const float* __restrict__ fb1,
    const float* __restrict__ fw21, const float* __restrict__ fw22,
    float* __restrict__ plm, float* __restrict__ plv)
{
    __shared__ __align__(16) char smem[64 * 768];   // 48 KB swizzled A tile
    __shared__ float plmL[4][64];
    __shared__ float plvL[4][64];

    const int tid  = threadIdx.x;
    const int lane = tid & 63;
    const int wid  = tid >> 6;
    const int b    = blockIdx.x >> 2;
    const int s0   = (blockIdx.x & 3) << 6;

    {
        const float* rbase = rho + (size_t)(b * 256 + s0) * 256;
        #pragma unroll
        for (int i = 0; i < 8; ++i) {
            int cid = i * 256 + tid;
            int r = cid >> 5, kc = cid & 31;
            const float4* gp = (const float4*)(rbase + r * 256 + kc * 8);
            float4 f0 = gp[0], f1 = gp[1];
            bf16x8 h;
            h[0] = f2bf(f0.x); h[1] = f2bf(f0.y); h[2] = f2bf(f0.z); h[3] = f2bf(f0.w);
            h[4] = f2bf(f1.x); h[5] = f2bf(f1.y); h[6] = f2bf(f1.z); h[7] = f2bf(f1.w);
            int byte = (r * 768 + kc * 16) ^ ((r & 7) << 4);
            *(bf16x8*)(smem + byte) = h;
        }
        const short* cbase = ctr + b * 128;
        #pragma unroll
        for (int i = 0; i < 4; ++i) {
            int cid = i * 256 + tid;
            int r = cid >> 4, kc = cid & 15;
            bf16x8 h = *(const bf16x8*)(cbase + kc * 8);
            int byte = (r * 768 + 512 + kc * 16) ^ ((r & 7) << 4);
            *(bf16x8*)(smem + byte) = h;
        }
    }

    float b1r[4][2], w21r[4][2], w22r[4][2];
    #pragma unroll
    for (int nc = 0; nc < 4; ++nc)
        #pragma unroll
        for (int cf = 0; cf < 2; ++cf) {
            int col = nc * 128 + wid * 32 + cf * 16 + (lane & 15);
            b1r[nc][cf]  = fb1[col];
            w21r[nc][cf] = fw21[col];
            w22r[nc][cf] = fw22[col];
        }

    __syncthreads();

    float plm_r[4][4], plv_r[4][4];
    #pragma unroll
    for (int rf = 0; rf < 4; ++rf)
        #pragma unroll
        for (int q = 0; q < 4; ++q) { plm_r[rf][q] = 0.f; plv_r[rf][q] = 0.f; }

    const short* bbase = w1t + (size_t)(wid * 32 + (lane & 15)) * 384 + (lane >> 4) * 8;

    for (int nc = 0; nc < 4; ++nc) {
        f32x4 acc[4][2];
        #pragma unroll
        for (int rf = 0; rf < 4; ++rf) {
            acc[rf][0] = (f32x4){0.f, 0.f, 0.f, 0.f};
            acc[rf][1] = (f32x4){0.f, 0.f, 0.f, 0.f};
        }
        const short* bn = bbase + (size_t)nc * 128 * 384;
        #pragma unroll
        for (int ks = 0; ks < 12; ++ks) {
            bf16x8 bf0 = *(const bf16x8*)(bn + ks * 32);
            bf16x8 bf1 = *(const bf16x8*)(bn + 16 * 384 + ks * 32);
            int ko = ks * 64 + (lane >> 4) * 16;
            #pragma unroll
            for (int rf = 0; rf < 4; ++rf) {
                int r = rf * 16 + (lane & 15);
                bf16x8 af = *(const bf16x8*)(smem + ((r * 768 + ko) ^ ((r & 7) << 4)));
                acc[rf][0] = __builtin_amdgcn_mfma_f32_16x16x32_bf16(af, bf0, acc[rf][0], 0, 0, 0);
                acc[rf][1] = __builtin_amdgcn_mfma_f32_16x16x32_bf16(af, bf1, acc[rf][1], 0, 0, 0);
            }
        }
        #pragma unroll
        for (int rf = 0; rf < 4; ++rf)
            #pragma unroll
            for (int q = 0; q < 4; ++q) {
                float sv0 = selu_f(acc[rf][0][q] + b1r[nc][0]);
                float sv1 = selu_f(acc[rf][1][q] + b1r[nc][1]);
                float cm = sv0 * w21r[nc][0] + sv1 * w21r[nc][1];
                float cv = sv0 * w22r[nc][0] + sv1 * w22r[nc][1];
                #pragma unroll
                for (int m = 1; m < 16; m <<= 1) {
                    cm += __shfl_xor(cm, m);
                    cv += __shfl_xor(cv, m);
                }
                plm_r[rf][q] += cm;
                plv_r[rf][q] += cv;
            }
    }

    if ((lane & 15) == 0) {
        int g = lane >> 4;
        #pragma unroll
        for (int rf = 0; rf < 4; ++rf)
            #pragma unroll
            for (int q = 0; q < 4; ++q) {
                int row = rf * 16 + g * 4 + q;
                plmL[wid][row] = plm_r[rf][q];
                plvL[wid][row] = plv_r[rf][q];
            }
    }
    __syncthreads();
    size_t obase = (size_t)b * 256 + s0;
    if (tid < 64) {
        plm[obase + tid] = plmL[0][tid] + plmL[1][tid] + plmL[2][tid] + plmL[3][tid];
    } else if (tid < 128) {
        int r = tid - 64;
        plv[obase + r] = plvL[0][r] + plvL[1][r] + plvL[2][r] + plvL[3][r];
    }
}

// ---------------------------------------------------------------------------
// Kernel 4: per-b logsumexp over S=256 and final outputs (1 wave per b)
// ---------------------------------------------------------------------------
__global__ void __launch_bounds__(64) finalize_kernel(
    const float* __restrict__ plm, const float* __restrict__ plv,
    const float* __restrict__ w, const float* __restrict__ l,
    const float* __restrict__ b21p, const float* __restrict__ b22p,
    float* __restrict__ out)
{
    const int b = blockIdx.x;
    const int lane = threadIdx.x;
    const float b21 = b21p[0], b22 = b22p[0];

    float a1[4], a2[4];
    float m1 = -1e30f, m2 = -1e30f;
    #pragma unroll
    for (int i = 0; i < 4; ++i) {
        int s = i * 64 + lane;
        float lw = logf(w[b * 256 + s]);
        a1[i] = plm[b * 256 + s] + b21 + lw;
        a2[i] = plv[b * 256 + s] + b22 + 2.f * lw;
        m1 = fmaxf(m1, a1[i]);
        m2 = fmaxf(m2, a2[i]);
    }
    #pragma unroll
    for (int m = 1; m < 64; m <<= 1) {
        m1 = fmaxf(m1, __shfl_xor(m1, m));
        m2 = fmaxf(m2, __shfl_xor(m2, m));
    }
    float s1 = 0.f, s2 = 0.f;
    #pragma unroll
    for (int i = 0; i < 4; ++i) {
        s1 += expf(a1[i] - m1);
        s2 += expf(a2[i] - m2);
    }
    #pragma unroll
    for (int m = 1; m < 64; m <<= 1) {
        s1 += __shfl_xor(s1, m);
        s2 += __shfl_xor(s2, m);
    }
    if (lane == 0) {
        float lm_agg = m1 + logf(s1);
        float lv_agg = m2 + logf(s2);
        float logl = logf(l[b]);
        out[b]       = logl - lm_agg;
        out[512 + b] = logl - 3.f * lm_agg - lv_agg;
    }
}

extern "C" void kernel_launch(void* const* d_in, const int* in_sizes, int n_in,
                              void* d_out, int out_size, void* d_ws, size_t ws_size,
                              hipStream_t stream) {
    const float* rho     = (const float*)d_in[0];
    const float* c       = (const float*)d_in[1];
    const float* w       = (const float*)d_in[2];
    const float* l       = (const float*)d_in[3];
    // d_in[4] = roads (unused by the reference)
    const int*   lon_idx = (const int*)d_in[5];
    const int*   lat_idx = (const int*)d_in[6];
    const float* f2W1    = (const float*)d_in[7];
    const float* f2b1    = (const float*)d_in[8];
    const float* f2W2    = (const float*)d_in[9];
    const float* f2b2    = (const float*)d_in[10];
    const float* fW1     = (const float*)d_in[11];
    const float* fb1     = (const float*)d_in[12];
    const float* fW21    = (const float*)d_in[13];
    const float* fb21    = (const float*)d_in[14];
    const float* fW22    = (const float*)d_in[15];
    const float* fb22    = (const float*)d_in[16];
    float* out = (float*)d_out;

    char* ws = (char*)d_ws;
    short* ctr = (short*)(ws);             // 131072 B
    short* w1t = (short*)(ws + 131072);    // 393216 B
    float* plm = (float*)(ws + 524288);    // 524288 B
    float* plv = (float*)(ws + 1048576);   // 524288 B

    prep_ctr_kernel<<<512, 256, 0, stream>>>(c, lat_idx, lon_idx,
                                             f2W1, f2b1, f2W2, f2b2, ctr);
    transpose_w1_kernel<<<768, 256, 0, stream>>>(fW1, w1t);
    fused_gemm_kernel<<<2048, 256, 0, stream>>>(rho, ctr, w1t, fb1, fW21, fW22,
                                                plm, plv);
    finalize_kernel<<<512, 64, 0, stream>>>(plm, plv, w, l, fb21, fb22, out);
}

// Round 2
// 118.165 us; speedup vs baseline: 2.5778x; 2.5778x over previous
//
#include <hip/hip_runtime.h>
#include <hip/hip_bf16.h>

typedef short bf16x8 __attribute__((ext_vector_type(8)));
typedef float f32x4 __attribute__((ext_vector_type(4)));

__device__ __forceinline__ short f2bf(float f) {
    union { float f; unsigned u; } v; v.f = f;
    unsigned r = (v.u + 0x7FFFu + ((v.u >> 16) & 1u)) >> 16;
    return (short)r;
}

__device__ __forceinline__ float selu_f(float x) {
    const float scale = 1.0507009873554805f;
    const float sa = 1.0507009873554805f * 1.6732632423543772f;
    return x > 0.f ? scale * x : sa * (__expf(x) - 1.f);
}

__device__ __forceinline__ void gld_lds16(const char* g, char* l) {
    __builtin_amdgcn_global_load_lds(
        (const __attribute__((address_space(1))) unsigned int*)g,
        (__attribute__((address_space(3))) unsigned int*)l, 16, 0, 0);
}

// ---------------------------------------------------------------------------
// Kernel 1: gather-mean over trajectory cells + f2 MLP (selu), bf16 out
// ---------------------------------------------------------------------------
__global__ void __launch_bounds__(256) prep_ctr_kernel(
    const float* __restrict__ c, const int* __restrict__ lat_idx,
    const int* __restrict__ lon_idx, const float* __restrict__ W1,
    const float* __restrict__ B1, const float* __restrict__ W2,
    const float* __restrict__ B2, short* __restrict__ ctr)
{
    __shared__ int cells[64];
    __shared__ float ctraj[128];
    __shared__ float hbuf[256];
    const int b = blockIdx.x;
    const int t = threadIdx.x;

    if (t < 64) cells[t] = lat_idx[b * 64 + t] * 17 + lon_idx[b * 64 + t];
    __syncthreads();

    if (t < 128) {
        float s = 0.f;
        #pragma unroll 8
        for (int j = 0; j < 64; ++j) s += c[t * 289 + cells[j]];
        ctraj[t] = s * (1.f / 64.f);
    }
    __syncthreads();

    {
        float acc = B1[t];
        #pragma unroll 8
        for (int i = 0; i < 128; ++i) acc += ctraj[i] * W1[i * 256 + t];
        hbuf[t] = selu_f(acc);
    }
    __syncthreads();

    if (t < 128) {
        float acc = B2[t];
        #pragma unroll 8
        for (int i = 0; i < 256; ++i) acc += hbuf[i] * W2[i * 128 + t];
        ctr[b * 128 + t] = f2bf(acc);
    }
}

// ---------------------------------------------------------------------------
// Kernel 2: f_W1 (384,512) f32 -> pre-swizzled bf16 image for global_load_lds
// Layout (shorts): I = kc*32768 + col*64 + s*8 + e   (col 0..511 incl group)
//   content = W1[(kc*64 + (s ^ (col&7))*8 + e)][col]
// so that a LINEAR gload_lds into LDS[col_local*128 + s*16 ...] yields the
// XOR-swizzled tile read by ds_read_b128 at (col*128 + k8*16)^((col&7)<<4).
// ---------------------------------------------------------------------------
__global__ void __launch_bounds__(256) transpose_w1_kernel(
    const float* __restrict__ W1, short* __restrict__ w1t_sw)
{
    int I = blockIdx.x * 256 + threadIdx.x;   // 0 .. 196607
    int kc = I >> 15;
    int r1 = I & 32767;
    int col = r1 >> 6;
    int s = (r1 >> 3) & 7;
    int e = I & 7;
    int k = kc * 64 + ((s ^ (col & 7)) << 3) + e;
    w1t_sw[I] = f2bf(W1[k * 512 + col]);
}

// ---------------------------------------------------------------------------
// Kernel 3: fused GEMM (bf16 MFMA) + selu + W21/W22 row-dots
// 1024 blocks x 512 threads (8 waves, 2 row-waves x 4 col-waves)
// Block: 128 rows (one b, half of S), loops over 2 col-groups of 256 cols,
//        K in 6 chunks of 64 (k<256 from rho f32->bf16, k>=256 from ctr bf16)
// LDS: A [128][64] bf16 swizzled (16KB) + B [256][64] bf16 swizzled (32KB)
//      + cross-wave reduce 4KB = 52KB -> 2-3 blocks/CU with VGPR<=128
// ---------------------------------------------------------------------------
__global__ void __launch_bounds__(512, 4) fused_gemm_kernel(
    const float* __restrict__ rho, const short* __restrict__ ctr,
    const short* __restrict__ w1t_sw, const float* __restrict__ fb1,
    const float* __restrict__ fw21, const float* __restrict__ fw22,
    float* __restrict__ plm, float* __restrict__ plv)
{
    __shared__ __align__(16) char smem[53248];
    float* redM = (float*)(smem + 49152);             // [4][128]
    float* redV = (float*)(smem + 49152 + 2048);      // [4][128]

    const int tid  = threadIdx.x;
    const int lane = tid & 63;
    const int wid  = tid >> 6;       // 0..7
    const int wr   = wid >> 2;       // 0..1 row-wave
    const int wc   = wid & 3;        // 0..3 col-wave
    const int l15  = lane & 15;
    const int hi16 = (lane >> 4) * 16;
    const int swl  = (lane & 7) << 4;

    const int rt = blockIdx.x;       // 0..1023
    const int b  = rt >> 1;
    const int s0 = (rt & 1) << 7;

    // staging roles: thread t stages row r = t>>2, k-segment seg = t&3 (16 k)
    const int r   = tid >> 2;
    const int seg = tid & 3;
    const float* ag = rho + (size_t)(b * 256 + s0 + r) * 256 + seg * 16;
    const short* cg = ctr + b * 128 + seg * 16;
    const int awb0 = (r * 128 + ((seg * 32) ^ ((r & 7) << 4)));
    const int awb1 = (r * 128 + ((seg * 32 + 16) ^ ((r & 7) << 4)));
    const char* wsw = (const char*)w1t_sw;

    #pragma unroll 1
    for (int gg = 0; gg < 2; ++gg) {
        f32x4 acc[4][4];
        #pragma unroll
        for (int rf = 0; rf < 4; ++rf)
            #pragma unroll
            for (int cf = 0; cf < 4; ++cf)
                acc[rf][cf] = (f32x4){0.f, 0.f, 0.f, 0.f};

        #pragma unroll 1
        for (int kc = 0; kc < 6; ++kc) {
            // ---- stage B via global_load_lds (issue first, independent) ----
            {
                const char* bsrc = wsw + kc * 65536 + gg * 32768;
                #pragma unroll
                for (int j = 0; j < 4; ++j) {
                    int off = (wid * 4 + j) * 1024;
                    gld_lds16(bsrc + off + lane * 16, smem + 16384 + off);
                }
            }
            // ---- stage A (reg + convert) ----
            if (kc < 4) {
                const float* a0 = ag + kc * 64;
                float4 f0 = *(const float4*)(a0);
                float4 f1 = *(const float4*)(a0 + 4);
                float4 f2 = *(const float4*)(a0 + 8);
                float4 f3 = *(const float4*)(a0 + 12);
                bf16x8 h0, h1;
                h0[0] = f2bf(f0.x); h0[1] = f2bf(f0.y); h0[2] = f2bf(f0.z); h0[3] = f2bf(f0.w);
                h0[4] = f2bf(f1.x); h0[5] = f2bf(f1.y); h0[6] = f2bf(f1.z); h0[7] = f2bf(f1.w);
                h1[0] = f2bf(f2.x); h1[1] = f2bf(f2.y); h1[2] = f2bf(f2.z); h1[3] = f2bf(f2.w);
                h1[4] = f2bf(f3.x); h1[5] = f2bf(f3.y); h1[6] = f2bf(f3.z); h1[7] = f2bf(f3.w);
                *(bf16x8*)(smem + awb0) = h0;
                *(bf16x8*)(smem + awb1) = h1;
            } else {
                const short* c0 = cg + (kc - 4) * 64;
                *(bf16x8*)(smem + awb0) = *(const bf16x8*)(c0);
                *(bf16x8*)(smem + awb1) = *(const bf16x8*)(c0 + 8);
            }
            __syncthreads();   // drains vmcnt (gload_lds) + lgkmcnt (A writes)

            // ---- compute: 32 MFMA from LDS ----
            #pragma unroll
            for (int ks = 0; ks < 2; ++ks) {
                const int abase = ks * 64 + hi16;
                bf16x8 aF[4], bF[4];
                #pragma unroll
                for (int rf = 0; rf < 4; ++rf) {
                    int row = wr * 64 + rf * 16 + l15;
                    aF[rf] = *(const bf16x8*)(smem + ((row * 128 + abase) ^ swl));
                }
                #pragma unroll
                for (int cf = 0; cf < 4; ++cf) {
                    int col = wc * 64 + cf * 16 + l15;
                    bF[cf] = *(const bf16x8*)(smem + 16384 + ((col * 128 + abase) ^ swl));
                }
                #pragma unroll
                for (int rf = 0; rf < 4; ++rf)
                    #pragma unroll
                    for (int cf = 0; cf < 4; ++cf)
                        acc[rf][cf] = __builtin_amdgcn_mfma_f32_16x16x32_bf16(
                            aF[rf], bF[cf], acc[rf][cf], 0, 0, 0);
            }
            __syncthreads();   // protect LDS before next chunk's staging
        }

        // ---- epilogue for this col-group: selu + dots + 16-lane reduce ----
        float b1r[4], w21r[4], w22r[4];
        #pragma unroll
        for (int cf = 0; cf < 4; ++cf) {
            int col = gg * 256 + wc * 64 + cf * 16 + l15;
            b1r[cf]  = fb1[col];
            w21r[cf] = fw21[col];
            w22r[cf] = fw22[col];
        }
        #pragma unroll
        for (int rf = 0; rf < 4; ++rf)
            #pragma unroll
            for (int q = 0; q < 4; ++q) {
                float m = 0.f, v = 0.f;
                #pragma unroll
                for (int cf = 0; cf < 4; ++cf) {
                    float s_ = selu_f(acc[rf][cf][q] + b1r[cf]);
                    m += s_ * w21r[cf];
                    v += s_ * w22r[cf];
                }
                #pragma unroll
                for (int d = 1; d < 16; d <<= 1) {
                    m += __shfl_xor(m, d);
                    v += __shfl_xor(v, d);
                }
                if (l15 == 0) {
                    int row = wr * 64 + rf * 16 + (lane >> 4) * 4 + q;
                    if (gg == 0) {
                        redM[wc * 128 + row] = m;
                        redV[wc * 128 + row] = v;
                    } else {
                        redM[wc * 128 + row] += m;
                        redV[wc * 128 + row] += v;
                    }
                }
            }
    }

    __syncthreads();
    size_t obase = (size_t)b * 256 + s0;
    if (tid < 128) {
        plm[obase + tid] = redM[tid] + redM[128 + tid] + redM[256 + tid] + redM[384 + tid];
    } else if (tid < 256) {
        int rr = tid - 128;
        plv[obase + rr] = redV[rr] + redV[128 + rr] + redV[256 + rr] + redV[384 + rr];
    }
}

// ---------------------------------------------------------------------------
// Kernel 4: per-b logsumexp over S=256 and final outputs (1 wave per b)
// ---------------------------------------------------------------------------
__global__ void __launch_bounds__(64) finalize_kernel(
    const float* __restrict__ plm, const float* __restrict__ plv,
    const float* __restrict__ w, const float* __restrict__ l,
    const float* __restrict__ b21p, const float* __restrict__ b22p,
    float* __restrict__ out)
{
    const int b = blockIdx.x;
    const int lane = threadIdx.x;
    const float b21 = b21p[0], b22 = b22p[0];

    float a1[4], a2[4];
    float m1 = -1e30f, m2 = -1e30f;
    #pragma unroll
    for (int i = 0; i < 4; ++i) {
        int s = i * 64 + lane;
        float lw = logf(w[b * 256 + s]);
        a1[i] = plm[b * 256 + s] + b21 + lw;
        a2[i] = plv[b * 256 + s] + b22 + 2.f * lw;
        m1 = fmaxf(m1, a1[i]);
        m2 = fmaxf(m2, a2[i]);
    }
    #pragma unroll
    for (int m = 1; m < 64; m <<= 1) {
        m1 = fmaxf(m1, __shfl_xor(m1, m));
        m2 = fmaxf(m2, __shfl_xor(m2, m));
    }
    float s1 = 0.f, s2 = 0.f;
    #pragma unroll
    for (int i = 0; i < 4; ++i) {
        s1 += expf(a1[i] - m1);
        s2 += expf(a2[i] - m2);
    }
    #pragma unroll
    for (int m = 1; m < 64; m <<= 1) {
        s1 += __shfl_xor(s1, m);
        s2 += __shfl_xor(s2, m);
    }
    if (lane == 0) {
        float lm_agg = m1 + logf(s1);
        float lv_agg = m2 + logf(s2);
        float logl = logf(l[b]);
        out[b]       = logl - lm_agg;
        out[512 + b] = logl - 3.f * lm_agg - lv_agg;
    }
}

extern "C" void kernel_launch(void* const* d_in, const int* in_sizes, int n_in,
                              void* d_out, int out_size, void* d_ws, size_t ws_size,
                              hipStream_t stream) {
    const float* rho     = (const float*)d_in[0];
    const float* c       = (const float*)d_in[1];
    const float* w       = (const float*)d_in[2];
    const float* l       = (const float*)d_in[3];
    // d_in[4] = roads (unused by the reference)
    const int*   lon_idx = (const int*)d_in[5];
    const int*   lat_idx = (const int*)d_in[6];
    const float* f2W1    = (const float*)d_in[7];
    const float* f2b1    = (const float*)d_in[8];
    const float* f2W2    = (const float*)d_in[9];
    const float* f2b2    = (const float*)d_in[10];
    const float* fW1     = (const float*)d_in[11];
    const float* fb1     = (const float*)d_in[12];
    const float* fW21    = (const float*)d_in[13];
    const float* fb21    = (const float*)d_in[14];
    const float* fW22    = (const float*)d_in[15];
    const float* fb22    = (const float*)d_in[16];
    float* out = (float*)d_out;

    char* ws = (char*)d_ws;
    short* ctr    = (short*)(ws);              // 131072 B
    short* w1t_sw = (short*)(ws + 131072);     // 393216 B
    float* plm    = (float*)(ws + 524288);     // 524288 B
    float* plv    = (float*)(ws + 1048576);    // 524288 B

    prep_ctr_kernel<<<512, 256, 0, stream>>>(c, lat_idx, lon_idx,
                                             f2W1, f2b1, f2W2, f2b2, ctr);
    transpose_w1_kernel<<<768, 256, 0, stream>>>(fW1, w1t_sw);
    fused_gemm_kernel<<<1024, 512, 0, stream>>>(rho, ctr, w1t_sw, fb1, fW21, fW22,
                                                plm, plv);
    finalize_kernel<<<512, 64, 0, stream>>>(plm, plv, w, l, fb21, fb22, out);
}

// Round 3
// 116.815 us; speedup vs baseline: 2.6076x; 1.0116x over previous
//
#include <hip/hip_runtime.h>
#include <hip/hip_bf16.h>

typedef short bf16x8 __attribute__((ext_vector_type(8)));
typedef float f32x4 __attribute__((ext_vector_type(4)));

__device__ __forceinline__ short f2bf(float f) {
    union { float f; unsigned u; } v; v.f = f;
    unsigned r = (v.u + 0x7FFFu + ((v.u >> 16) & 1u)) >> 16;
    return (short)r;
}

__device__ __forceinline__ float selu_f(float x) {
    const float scale = 1.0507009873554805f;
    const float sa = 1.0507009873554805f * 1.6732632423543772f;
    return x > 0.f ? scale * x : sa * (__expf(x) - 1.f);
}

// global src addr is per-lane (include lane*16); LDS base is wave-uniform,
// HW adds lane*16 to the LDS destination.
__device__ __forceinline__ void gld_lds16(const char* g, char* l) {
    __builtin_amdgcn_global_load_lds(
        (const __attribute__((address_space(1))) unsigned int*)g,
        (__attribute__((address_space(3))) unsigned int*)l, 16, 0, 0);
}

// ---------------------------------------------------------------------------
// Kernel 1: gather-mean + f2 MLP + cbias[b][col] = ctr_f32 @ W1[256:384,:] + b1
// 512 blocks x 512 threads. cbias exact in f32 -> K of the big GEMM drops to 256.
// ---------------------------------------------------------------------------
__global__ void __launch_bounds__(512) prep_cbias_kernel(
    const float* __restrict__ c, const int* __restrict__ lat_idx,
    const int* __restrict__ lon_idx,
    const float* __restrict__ f2W1, const float* __restrict__ f2b1,
    const float* __restrict__ f2W2, const float* __restrict__ f2b2,
    const float* __restrict__ fW1, const float* __restrict__ fb1,
    float* __restrict__ cbias)
{
    __shared__ int cells[64];
    __shared__ float ctraj[128];
    __shared__ float hbuf[256];
    __shared__ float ctrf[128];
    const int b = blockIdx.x;
    const int t = threadIdx.x;

    if (t < 64) cells[t] = lat_idx[b * 64 + t] * 17 + lon_idx[b * 64 + t];
    __syncthreads();

    if (t < 128) {
        float s = 0.f;
        #pragma unroll 8
        for (int j = 0; j < 64; ++j) s += c[t * 289 + cells[j]];
        ctraj[t] = s * (1.f / 64.f);
    }
    __syncthreads();

    if (t < 256) {
        float acc = f2b1[t];
        #pragma unroll 8
        for (int i = 0; i < 128; ++i) acc += ctraj[i] * f2W1[i * 256 + t];
        hbuf[t] = selu_f(acc);
    }
    __syncthreads();

    if (t < 128) {
        float acc = f2b2[t];
        #pragma unroll 8
        for (int i = 0; i < 256; ++i) acc += hbuf[i] * f2W2[i * 128 + t];
        ctrf[t] = acc;
    }
    __syncthreads();

    // cbias for col t (0..511)
    float acc = fb1[t];
    #pragma unroll 8
    for (int i = 0; i < 128; ++i) acc += ctrf[i] * fW1[(256 + i) * 512 + t];
    cbias[b * 512 + t] = acc;
}

// ---------------------------------------------------------------------------
// Kernel 2: W1[0:256,:] f32 -> fragment-major bf16 image.
// slot I = ((kc*32 + cg)*64 + lane)*8 + e  holds W1[kc*32+(lane>>4)*8+e][cg*16+(lane&15)]
// so global_load_lds (linear) -> LDS and ds_read_b128 at base+lane*16 are both
// conflict-free, no swizzle anywhere.
// ---------------------------------------------------------------------------
__global__ void __launch_bounds__(256) build_w1img_kernel(
    const float* __restrict__ fW1, short* __restrict__ img)
{
    int I = blockIdx.x * 256 + threadIdx.x;  // 0 .. 131071
    int e = I & 7;
    int lane = (I >> 3) & 63;
    int cg = (I >> 9) & 31;
    int kc = I >> 14;
    int col = cg * 16 + (lane & 15);
    int k = kc * 32 + ((lane >> 4) << 3) + e;
    img[I] = f2bf(fW1[k * 512 + col]);
}

// ---------------------------------------------------------------------------
// Kernel 3: fused GEMM (K=256) + selu + W21/W22 dots.
// 1024 blocks x 512 threads (8 waves = 2 row x 4 col, wave tile 64x128).
// LDS 128KB: A [8kc][8rg][64lane][16B] = 64KB resident, staged once;
//            B double-buffer 2 x 32KB, global_load_lds + counted vmcnt(4),
//            raw s_barrier (no vmcnt(0) drain in the K loop).
// ---------------------------------------------------------------------------
__global__ void __launch_bounds__(512, 2) fused_gemm_kernel(
    const float* __restrict__ rho, const short* __restrict__ w1img,
    const float* __restrict__ cbias, const float* __restrict__ fw21,
    const float* __restrict__ fw22,
    float* __restrict__ plm, float* __restrict__ plv)
{
    __shared__ __align__(16) char smem[131072];

    const int tid  = threadIdx.x;
    const int lane = tid & 63;
    const int wid  = tid >> 6;      // 0..7
    const int wr   = wid >> 2;      // 0..1
    const int wc   = wid & 3;       // 0..3
    const int l15  = lane & 15;
    const int hi   = lane >> 4;     // 0..3

    const int b  = blockIdx.x >> 1;
    const int s0 = (blockIdx.x & 1) << 7;

    const char* img = (const char*)w1img;
    char* bufA = smem;                 // 64 KB
    char* buf0 = smem + 65536;         // 32 KB
    char* buf1 = smem + 98304;         // 32 KB

    // ---- stage A once: wave w covers k-chunk kc=wid, rowgrps 0..7 ----
    {
        const float* src = rho + (size_t)(b * 256 + s0) * 256 + wid * 32 + hi * 8;
        float4 va[16];
        #pragma unroll
        for (int rg = 0; rg < 8; ++rg) {
            const float* p = src + (size_t)(rg * 16 + l15) * 256;
            va[2 * rg]     = *(const float4*)p;
            va[2 * rg + 1] = *(const float4*)(p + 4);
        }
        #pragma unroll
        for (int rg = 0; rg < 8; ++rg) {
            bf16x8 h;
            h[0] = f2bf(va[2*rg].x);   h[1] = f2bf(va[2*rg].y);
            h[2] = f2bf(va[2*rg].z);   h[3] = f2bf(va[2*rg].w);
            h[4] = f2bf(va[2*rg+1].x); h[5] = f2bf(va[2*rg+1].y);
            h[6] = f2bf(va[2*rg+1].z); h[7] = f2bf(va[2*rg+1].w);
            *(bf16x8*)(bufA + ((wid * 8 + rg) * 64 + lane) * 16) = h;
        }
    }

    // ---- issue B chunk 0 ----
    #pragma unroll
    for (int j = 0; j < 4; ++j) {
        int cg = wid * 4 + j;
        gld_lds16(img + (size_t)cg * 1024 + lane * 16, buf0 + cg * 1024);
    }

    __syncthreads();   // one-time full drain: A visible, B0 landed

    f32x4 acc[4][8];
    #pragma unroll
    for (int rf = 0; rf < 4; ++rf)
        #pragma unroll
        for (int cf = 0; cf < 8; ++cf)
            acc[rf][cf] = (f32x4){0.f, 0.f, 0.f, 0.f};

    #pragma unroll 1
    for (int kc = 0; kc < 8; ++kc) {
        // A fragments for this k-chunk (static region, safe anywhere)
        bf16x8 aF[4];
        #pragma unroll
        for (int rf = 0; rf < 4; ++rf)
            aF[rf] = *(const bf16x8*)(bufA + ((kc * 8 + wr * 4 + rf) * 64 + lane) * 16);

        // prefetch next B chunk into the other buffer
        if (kc < 7) {
            const char* src = img + (size_t)(kc + 1) * 32768;
            char* dst = ((kc + 1) & 1) ? buf1 : buf0;
            #pragma unroll
            for (int j = 0; j < 4; ++j) {
                int cg = wid * 4 + j;
                gld_lds16(src + (size_t)cg * 1024 + lane * 16, dst + cg * 1024);
            }
            asm volatile("s_waitcnt vmcnt(4)" ::: "memory");   // current chunk landed
        } else {
            asm volatile("s_waitcnt vmcnt(0)" ::: "memory");
        }
        __builtin_amdgcn_s_barrier();      // all waves: B(kc) landed
        asm volatile("" ::: "memory");

        const char* bb = (kc & 1) ? buf1 : buf0;
        bf16x8 bF[8];
        #pragma unroll
        for (int cf = 0; cf < 8; ++cf)
            bF[cf] = *(const bf16x8*)(bb + (wc * 8 + cf) * 1024 + lane * 16);

        #pragma unroll
        for (int rf = 0; rf < 4; ++rf)
            #pragma unroll
            for (int cf = 0; cf < 8; ++cf)
                acc[rf][cf] = __builtin_amdgcn_mfma_f32_16x16x32_bf16(
                    aF[rf], bF[cf], acc[rf][cf], 0, 0, 0);

        asm volatile("" ::: "memory");
        __builtin_amdgcn_s_barrier();      // frees buf[kc&1] for kc+2 staging
    }

    // ---- epilogue: selu + W21/W22 dots + 16-lane col reduce ----
    float cb[8], w21r[8], w22r[8];
    #pragma unroll
    for (int cf = 0; cf < 8; ++cf) {
        int col = wc * 128 + cf * 16 + l15;
        cb[cf]   = cbias[b * 512 + col];
        w21r[cf] = fw21[col];
        w22r[cf] = fw22[col];
    }

    float pm[4][4], pv[4][4];
    #pragma unroll
    for (int rf = 0; rf < 4; ++rf)
        #pragma unroll
        for (int q = 0; q < 4; ++q) {
            float m = 0.f, v = 0.f;
            #pragma unroll
            for (int cf = 0; cf < 8; ++cf) {
                float s_ = selu_f(acc[rf][cf][q] + cb[cf]);
                m += s_ * w21r[cf];
                v += s_ * w22r[cf];
            }
            #pragma unroll
            for (int d = 1; d < 16; d <<= 1) {
                m += __shfl_xor(m, d);
                v += __shfl_xor(v, d);
            }
            pm[rf][q] = m;
            pv[rf][q] = v;
        }

    __syncthreads();   // done with B buffers; reuse as reduction scratch
    float* redM = (float*)(smem + 65536);          // [4][128]
    float* redV = (float*)(smem + 65536 + 2048);   // [4][128]
    if (l15 == 0) {
        #pragma unroll
        for (int rf = 0; rf < 4; ++rf)
            #pragma unroll
            for (int q = 0; q < 4; ++q) {
                int row = wr * 64 + rf * 16 + hi * 4 + q;
                redM[wc * 128 + row] = pm[rf][q];
                redV[wc * 128 + row] = pv[rf][q];
            }
    }
    __syncthreads();
    size_t obase = (size_t)b * 256 + s0;
    if (tid < 128) {
        plm[obase + tid] = redM[tid] + redM[128 + tid] + redM[256 + tid] + redM[384 + tid];
    } else if (tid < 256) {
        int rr = tid - 128;
        plv[obase + rr] = redV[rr] + redV[128 + rr] + redV[256 + rr] + redV[384 + rr];
    }
}

// ---------------------------------------------------------------------------
// Kernel 4: per-b logsumexp over S=256 and final outputs (1 wave per b)
// ---------------------------------------------------------------------------
__global__ void __launch_bounds__(64) finalize_kernel(
    const float* __restrict__ plm, const float* __restrict__ plv,
    const float* __restrict__ w, const float* __restrict__ l,
    const float* __restrict__ b21p, const float* __restrict__ b22p,
    float* __restrict__ out)
{
    const int b = blockIdx.x;
    const int lane = threadIdx.x;
    const float b21 = b21p[0], b22 = b22p[0];

    float a1[4], a2[4];
    float m1 = -1e30f, m2 = -1e30f;
    #pragma unroll
    for (int i = 0; i < 4; ++i) {
        int s = i * 64 + lane;
        float lw = logf(w[b * 256 + s]);
        a1[i] = plm[b * 256 + s] + b21 + lw;
        a2[i] = plv[b * 256 + s] + b22 + 2.f * lw;
        m1 = fmaxf(m1, a1[i]);
        m2 = fmaxf(m2, a2[i]);
    }
    #pragma unroll
    for (int m = 1; m < 64; m <<= 1) {
        m1 = fmaxf(m1, __shfl_xor(m1, m));
        m2 = fmaxf(m2, __shfl_xor(m2, m));
    }
    float s1 = 0.f, s2 = 0.f;
    #pragma unroll
    for (int i = 0; i < 4; ++i) {
        s1 += expf(a1[i] - m1);
        s2 += expf(a2[i] - m2);
    }
    #pragma unroll
    for (int m = 1; m < 64; m <<= 1) {
        s1 += __shfl_xor(s1, m);
        s2 += __shfl_xor(s2, m);
    }
    if (lane == 0) {
        float lm_agg = m1 + logf(s1);
        float lv_agg = m2 + logf(s2);
        float logl = logf(l[b]);
        out[b]       = logl - lm_agg;
        out[512 + b] = logl - 3.f * lm_agg - lv_agg;
    }
}

extern "C" void kernel_launch(void* const* d_in, const int* in_sizes, int n_in,
                              void* d_out, int out_size, void* d_ws, size_t ws_size,
                              hipStream_t stream) {
    const float* rho     = (const float*)d_in[0];
    const float* c       = (const float*)d_in[1];
    const float* w       = (const float*)d_in[2];
    const float* l       = (const float*)d_in[3];
    // d_in[4] = roads (unused by the reference)
    const int*   lon_idx = (const int*)d_in[5];
    const int*   lat_idx = (const int*)d_in[6];
    const float* f2W1    = (const float*)d_in[7];
    const float* f2b1    = (const float*)d_in[8];
    const float* f2W2    = (const float*)d_in[9];
    const float* f2b2    = (const float*)d_in[10];
    const float* fW1     = (const float*)d_in[11];
    const float* fb1     = (const float*)d_in[12];
    const float* fW21    = (const float*)d_in[13];
    const float* fb21    = (const float*)d_in[14];
    const float* fW22    = (const float*)d_in[15];
    const float* fb22    = (const float*)d_in[16];
    float* out = (float*)d_out;

    char* ws = (char*)d_ws;
    float* cbias  = (float*)(ws);               // 512*512*4  = 1048576 B
    short* w1img  = (short*)(ws + 1048576);     // 131072*2   =  262144 B
    float* plm    = (float*)(ws + 1310720);     // 512*256*4  =  524288 B
    float* plv    = (float*)(ws + 1835008);     // 512*256*4  =  524288 B
                                                // total 2359296 B

    prep_cbias_kernel<<<512, 512, 0, stream>>>(c, lat_idx, lon_idx,
                                               f2W1, f2b1, f2W2, f2b2,
                                               fW1, fb1, cbias);
    build_w1img_kernel<<<512, 256, 0, stream>>>(fW1, w1img);
    fused_gemm_kernel<<<1024, 512, 0, stream>>>(rho, w1img, cbias, fW21, fW22,
                                                plm, plv);
    finalize_kernel<<<512, 64, 0, stream>>>(plm, plv, w, l, fb21, fb22, out);
}

// Round 4
// 109.662 us; speedup vs baseline: 2.7776x; 1.0652x over previous
//
#include <hip/hip_runtime.h>
#include <hip/hip_bf16.h>

typedef short bf16x8 __attribute__((ext_vector_type(8)));
typedef float f32x4 __attribute__((ext_vector_type(4)));

__device__ __forceinline__ short f2bf(float f) {
    union { float f; unsigned u; } v; v.f = f;
    unsigned r = (v.u + 0x7FFFu + ((v.u >> 16) & 1u)) >> 16;
    return (short)r;
}

__device__ __forceinline__ float selu_f(float x) {
    const float scale = 1.0507009873554805f;
    const float sa = 1.0507009873554805f * 1.6732632423543772f;
    return x > 0.f ? scale * x : sa * (__expf(x) - 1.f);
}

// ---------------------------------------------------------------------------
// Kernel 1: gather-mean + f2 MLP + cbias[b][col] = ctr_f32 @ W1[256:384,:] + b1
// ---------------------------------------------------------------------------
__global__ void __launch_bounds__(512) prep_cbias_kernel(
    const float* __restrict__ c, const int* __restrict__ lat_idx,
    const int* __restrict__ lon_idx,
    const float* __restrict__ f2W1, const float* __restrict__ f2b1,
    const float* __restrict__ f2W2, const float* __restrict__ f2b2,
    const float* __restrict__ fW1, const float* __restrict__ fb1,
    float* __restrict__ cbias)
{
    __shared__ int cells[64];
    __shared__ float ctraj[128];
    __shared__ float hbuf[256];
    __shared__ float ctrf[128];
    const int b = blockIdx.x;
    const int t = threadIdx.x;

    if (t < 64) cells[t] = lat_idx[b * 64 + t] * 17 + lon_idx[b * 64 + t];
    __syncthreads();

    if (t < 128) {
        float s = 0.f;
        #pragma unroll 8
        for (int j = 0; j < 64; ++j) s += c[t * 289 + cells[j]];
        ctraj[t] = s * (1.f / 64.f);
    }
    __syncthreads();

    if (t < 256) {
        float acc = f2b1[t];
        #pragma unroll 8
        for (int i = 0; i < 128; ++i) acc += ctraj[i] * f2W1[i * 256 + t];
        hbuf[t] = selu_f(acc);
    }
    __syncthreads();

    if (t < 128) {
        float acc = f2b2[t];
        #pragma unroll 8
        for (int i = 0; i < 256; ++i) acc += hbuf[i] * f2W2[i * 128 + t];
        ctrf[t] = acc;
    }
    __syncthreads();

    float acc = fb1[t];
    #pragma unroll 8
    for (int i = 0; i < 128; ++i) acc += ctrf[i] * fW1[(256 + i) * 512 + t];
    cbias[b * 512 + t] = acc;
}

// ---------------------------------------------------------------------------
// Kernel 2: W1[0:256,:] f32 -> fragment-major bf16 image.
// slot I = ((kc*32 + cg)*64 + lane)*8 + e holds
//   W1[kc*32 + (lane>>4)*8 + e][cg*16 + (lane&15)]
// ---------------------------------------------------------------------------
__global__ void __launch_bounds__(256) build_w1img_kernel(
    const float* __restrict__ fW1, short* __restrict__ img)
{
    int I = blockIdx.x * 256 + threadIdx.x;  // 0 .. 131071
    int e = I & 7;
    int lane = (I >> 3) & 63;
    int cg = (I >> 9) & 31;
    int kc = I >> 14;
    int col = cg * 16 + (lane & 15);
    int k = kc * 32 + ((lane >> 4) << 3) + e;
    img[I] = f2bf(fW1[k * 512 + col]);
}

// ---------------------------------------------------------------------------
// Kernel 3: fused GEMM (K=256) + selu + W21/W22 dots.
// 2048 blocks x 256 threads (4 waves, each 64 rows x 128 cols).
// A: 32 KB fragment-major LDS, staged once, ONE barrier total before K-loop.
// B: plain per-lane global loads from L2-hot fragment-major image (no LDS,
//    no barriers, no gld_lds -> compiler pipelines freely).
// ---------------------------------------------------------------------------
__global__ void __launch_bounds__(256, 2) fused_gemm_kernel(
    const float* __restrict__ rho, const short* __restrict__ w1img,
    const float* __restrict__ cbias, const float* __restrict__ fw21,
    const float* __restrict__ fw22,
    float* __restrict__ plm, float* __restrict__ plv)
{
    __shared__ __align__(16) char smA[32768];   // [kc8][rg4][lane64][16B]
    __shared__ float redM[4][64];
    __shared__ float redV[4][64];

    const int tid  = threadIdx.x;
    const int lane = tid & 63;
    const int w    = tid >> 6;      // col-wave 0..3
    const int l15  = lane & 15;
    const int hi   = lane >> 4;     // 0..3

    const int b  = blockIdx.x >> 2;
    const int s0 = (blockIdx.x & 3) << 6;

    // ---- stage A once: slot s = i*256 + tid ----
    {
        const float* rbase = rho + (size_t)(b * 256 + s0) * 256;
        const int row  = ((tid >> 6) << 4) + (tid & 15);  // rg*16 + (t&15)
        const int kseg = (tid >> 4) & 3;                  // 8-float segment
        const float* src = rbase + (size_t)row * 256 + kseg * 8;
        #pragma unroll
        for (int i = 0; i < 8; ++i) {
            float4 f0 = *(const float4*)(src + i * 32);
            float4 f1 = *(const float4*)(src + i * 32 + 4);
            bf16x8 h;
            h[0] = f2bf(f0.x); h[1] = f2bf(f0.y); h[2] = f2bf(f0.z); h[3] = f2bf(f0.w);
            h[4] = f2bf(f1.x); h[5] = f2bf(f1.y); h[6] = f2bf(f1.z); h[7] = f2bf(f1.w);
            *(bf16x8*)(smA + (i * 256 + tid) * 16) = h;
        }
    }
    __syncthreads();   // the only block-wide barrier before the epilogue

    f32x4 acc[4][8];
    #pragma unroll
    for (int rf = 0; rf < 4; ++rf)
        #pragma unroll
        for (int cf = 0; cf < 8; ++cf)
            acc[rf][cf] = (f32x4){0.f, 0.f, 0.f, 0.f};

    // wave w covers col-tiles cg = w*8 .. w*8+7
    const char* bimg = (const char*)w1img + (size_t)w * 8192 + lane * 16;

    #pragma unroll
    for (int kc = 0; kc < 8; ++kc) {
        bf16x8 aF[4];
        #pragma unroll
        for (int rf = 0; rf < 4; ++rf)
            aF[rf] = *(const bf16x8*)(smA + ((kc * 4 + rf) * 64 + lane) * 16);
        bf16x8 bF[8];
        #pragma unroll
        for (int cf = 0; cf < 8; ++cf)
            bF[cf] = *(const bf16x8*)(bimg + (size_t)kc * 32768 + cf * 1024);
        #pragma unroll
        for (int rf = 0; rf < 4; ++rf)
            #pragma unroll
            for (int cf = 0; cf < 8; ++cf)
                acc[rf][cf] = __builtin_amdgcn_mfma_f32_16x16x32_bf16(
                    aF[rf], bF[cf], acc[rf][cf], 0, 0, 0);
    }

    // ---- epilogue: selu + W21/W22 dots + 16-lane col reduce ----
    float cb[8], w21r[8], w22r[8];
    #pragma unroll
    for (int cf = 0; cf < 8; ++cf) {
        int col = w * 128 + cf * 16 + l15;
        cb[cf]   = cbias[b * 512 + col];
        w21r[cf] = fw21[col];
        w22r[cf] = fw22[col];
    }

    #pragma unroll
    for (int rf = 0; rf < 4; ++rf)
        #pragma unroll
        for (int q = 0; q < 4; ++q) {
            float m = 0.f, v = 0.f;
            #pragma unroll
            for (int cf = 0; cf < 8; ++cf) {
                float s_ = selu_f(acc[rf][cf][q] + cb[cf]);
                m += s_ * w21r[cf];
                v += s_ * w22r[cf];
            }
            #pragma unroll
            for (int d = 1; d < 16; d <<= 1) {
                m += __shfl_xor(m, d);
                v += __shfl_xor(v, d);
            }
            if (l15 == 0) {
                int row = rf * 16 + hi * 4 + q;
                redM[w][row] = m;
                redV[w][row] = v;
            }
        }

    __syncthreads();
    size_t obase = (size_t)b * 256 + s0;
    if (tid < 64) {
        plm[obase + tid] = redM[0][tid] + redM[1][tid] + redM[2][tid] + redM[3][tid];
    } else if (tid < 128) {
        int rr = tid - 64;
        plv[obase + rr] = redV[0][rr] + redV[1][rr] + redV[2][rr] + redV[3][rr];
    }
}

// ---------------------------------------------------------------------------
// Kernel 4: per-b logsumexp over S=256 and final outputs (1 wave per b)
// ---------------------------------------------------------------------------
__global__ void __launch_bounds__(64) finalize_kernel(
    const float* __restrict__ plm, const float* __restrict__ plv,
    const float* __restrict__ w, const float* __restrict__ l,
    const float* __restrict__ b21p, const float* __restrict__ b22p,
    float* __restrict__ out)
{
    const int b = blockIdx.x;
    const int lane = threadIdx.x;
    const float b21 = b21p[0], b22 = b22p[0];

    float a1[4], a2[4];
    float m1 = -1e30f, m2 = -1e30f;
    #pragma unroll
    for (int i = 0; i < 4; ++i) {
        int s = i * 64 + lane;
        float lw = logf(w[b * 256 + s]);
        a1[i] = plm[b * 256 + s] + b21 + lw;
        a2[i] = plv[b * 256 + s] + b22 + 2.f * lw;
        m1 = fmaxf(m1, a1[i]);
        m2 = fmaxf(m2, a2[i]);
    }
    #pragma unroll
    for (int m = 1; m < 64; m <<= 1) {
        m1 = fmaxf(m1, __shfl_xor(m1, m));
        m2 = fmaxf(m2, __shfl_xor(m2, m));
    }
    float s1 = 0.f, s2 = 0.f;
    #pragma unroll
    for (int i = 0; i < 4; ++i) {
        s1 += expf(a1[i] - m1);
        s2 += expf(a2[i] - m2);
    }
    #pragma unroll
    for (int m = 1; m < 64; m <<= 1) {
        s1 += __shfl_xor(s1, m);
        s2 += __shfl_xor(s2, m);
    }
    if (lane == 0) {
        float lm_agg = m1 + logf(s1);
        float lv_agg = m2 + logf(s2);
        float logl = logf(l[b]);
        out[b]       = logl - lm_agg;
        out[512 + b] = logl - 3.f * lm_agg - lv_agg;
    }
}

extern "C" void kernel_launch(void* const* d_in, const int* in_sizes, int n_in,
                              void* d_out, int out_size, void* d_ws, size_t ws_size,
                              hipStream_t stream) {
    const float* rho     = (const float*)d_in[0];
    const float* c       = (const float*)d_in[1];
    const float* w       = (const float*)d_in[2];
    const float* l       = (const float*)d_in[3];
    // d_in[4] = roads (unused by the reference)
    const int*   lon_idx = (const int*)d_in[5];
    const int*   lat_idx = (const int*)d_in[6];
    const float* f2W1    = (const float*)d_in[7];
    const float* f2b1    = (const float*)d_in[8];
    const float* f2W2    = (const float*)d_in[9];
    const float* f2b2    = (const float*)d_in[10];
    const float* fW1     = (const float*)d_in[11];
    const float* fb1     = (const float*)d_in[12];
    const float* fW21    = (const float*)d_in[13];
    const float* fb21    = (const float*)d_in[14];
    const float* fW22    = (const float*)d_in[15];
    const float* fb22    = (const float*)d_in[16];
    float* out = (float*)d_out;

    char* ws = (char*)d_ws;
    float* cbias  = (float*)(ws);               // 1048576 B
    short* w1img  = (short*)(ws + 1048576);     //  262144 B
    float* plm    = (float*)(ws + 1310720);     //  524288 B
    float* plv    = (float*)(ws + 1835008);     //  524288 B

    prep_cbias_kernel<<<512, 512, 0, stream>>>(c, lat_idx, lon_idx,
                                               f2W1, f2b1, f2W2, f2b2,
                                               fW1, fb1, cbias);
    build_w1img_kernel<<<512, 256, 0, stream>>>(fW1, w1img);
    fused_gemm_kernel<<<2048, 256, 0, stream>>>(rho, w1img, cbias, fW21, fW22,
                                                plm, plv);
    finalize_kernel<<<512, 64, 0, stream>>>(plm, plv, w, l, fb21, fb22, out);
}

// Round 5
// 105.972 us; speedup vs baseline: 2.8744x; 1.0348x over previous
//
#include <hip/hip_runtime.h>
#include <hip/hip_bf16.h>

typedef short bf16x8 __attribute__((ext_vector_type(8)));
typedef float f32x4 __attribute__((ext_vector_type(4)));

__device__ __forceinline__ short f2bf(float f) {
    union { float f; unsigned u; } v; v.f = f;
    unsigned r = (v.u + 0x7FFFu + ((v.u >> 16) & 1u)) >> 16;
    return (short)r;
}

__device__ __forceinline__ float selu_f(float x) {
    const float scale = 1.0507009873554805f;
    const float sa = 1.0507009873554805f * 1.6732632423543772f;
    return x > 0.f ? scale * x : sa * (__expf(x) - 1.f);
}

// ---------------------------------------------------------------------------
// Kernel 1: gather-mean + f2 MLP + cbias[b][col] = ctr_f32 @ W1[256:384,:] + b1
// ---------------------------------------------------------------------------
__global__ void __launch_bounds__(512) prep_cbias_kernel(
    const float* __restrict__ c, const int* __restrict__ lat_idx,
    const int* __restrict__ lon_idx,
    const float* __restrict__ f2W1, const float* __restrict__ f2b1,
    const float* __restrict__ f2W2, const float* __restrict__ f2b2,
    const float* __restrict__ fW1, const float* __restrict__ fb1,
    float* __restrict__ cbias)
{
    __shared__ int cells[64];
    __shared__ float ctraj[128];
    __shared__ float hbuf[256];
    __shared__ float ctrf[128];
    const int b = blockIdx.x;
    const int t = threadIdx.x;

    if (t < 64) cells[t] = lat_idx[b * 64 + t] * 17 + lon_idx[b * 64 + t];
    __syncthreads();

    if (t < 128) {
        float s = 0.f;
        #pragma unroll 8
        for (int j = 0; j < 64; ++j) s += c[t * 289 + cells[j]];
        ctraj[t] = s * (1.f / 64.f);
    }
    __syncthreads();

    if (t < 256) {
        float acc = f2b1[t];
        #pragma unroll 8
        for (int i = 0; i < 128; ++i) acc += ctraj[i] * f2W1[i * 256 + t];
        hbuf[t] = selu_f(acc);
    }
    __syncthreads();

    if (t < 128) {
        float acc = f2b2[t];
        #pragma unroll 8
        for (int i = 0; i < 256; ++i) acc += hbuf[i] * f2W2[i * 128 + t];
        ctrf[t] = acc;
    }
    __syncthreads();

    float acc = fb1[t];
    #pragma unroll 8
    for (int i = 0; i < 128; ++i) acc += ctrf[i] * fW1[(256 + i) * 512 + t];
    cbias[b * 512 + t] = acc;
}

// ---------------------------------------------------------------------------
// Kernel 2: W1[0:256,:] f32 -> fragment-major bf16 image.
// slot I = ((kc*32 + cg)*64 + lane)*8 + e holds
//   W1[kc*32 + (lane>>4)*8 + e][cg*16 + (lane&15)]
// ---------------------------------------------------------------------------
__global__ void __launch_bounds__(256) build_w1img_kernel(
    const float* __restrict__ fW1, short* __restrict__ img)
{
    int I = blockIdx.x * 256 + threadIdx.x;  // 0 .. 131071
    int e = I & 7;
    int lane = (I >> 3) & 63;
    int cg = (I >> 9) & 31;
    int kc = I >> 14;
    int col = cg * 16 + (lane & 15);
    int k = kc * 32 + ((lane >> 4) << 3) + e;
    img[I] = f2bf(fW1[k * 512 + col]);
}

// ---------------------------------------------------------------------------
// Kernel 3: fused GEMM (K=256) + selu + W21/W22 dots.
// 2048 blocks x 512 threads (8 waves). Block tile 64 rows x 512 cols;
// wave w owns cols [w*64, w*64+64) -> acc 4x4 f32x4 = 64 regs/lane.
// A: 32 KB fragment-major LDS, staged once (one barrier).
// B: per-lane global loads from L2-hot image, one-kc-deep register dbuf.
// __launch_bounds__(512,4): 128-reg cap -> 4 waves/SIMD, 2 blocks/CU.
// ---------------------------------------------------------------------------
__global__ void __launch_bounds__(512, 4) fused_gemm_kernel(
    const float* __restrict__ rho, const short* __restrict__ w1img,
    const float* __restrict__ cbias, const float* __restrict__ fw21,
    const float* __restrict__ fw22,
    float* __restrict__ plm, float* __restrict__ plv)
{
    __shared__ __align__(16) char smA[32768];   // [kc8][rg4][lane64][16B]
    __shared__ float redM[8][64];
    __shared__ float redV[8][64];

    const int tid  = threadIdx.x;
    const int lane = tid & 63;
    const int w    = tid >> 6;      // col-wave 0..7
    const int l15  = lane & 15;
    const int hi   = lane >> 4;     // 0..3

    const int b  = blockIdx.x >> 2;
    const int s0 = (blockIdx.x & 2) << 5 | (blockIdx.x & 1) << 6;  // (blockIdx&3)*64
    // simpler: s0 = (blockIdx.x & 3) << 6
    const int s0v = (blockIdx.x & 3) << 6;

    // ---- stage A once: slot s = i*512 + tid, s = kc*256 + rg*64 + lane_s ----
    {
        const float* rbase = rho + (size_t)(b * 256 + s0v) * 256;
        #pragma unroll
        for (int i = 0; i < 4; ++i) {
            int slot = i * 512 + tid;
            int kc = slot >> 8;
            int rem = slot & 255;
            int rg = rem >> 6;
            int ls = rem & 63;
            int row = rg * 16 + (ls & 15);
            int k0 = kc * 32 + ((ls >> 4) << 3);
            const float* src = rbase + (size_t)row * 256 + k0;
            float4 f0 = *(const float4*)(src);
            float4 f1 = *(const float4*)(src + 4);
            bf16x8 h;
            h[0] = f2bf(f0.x); h[1] = f2bf(f0.y); h[2] = f2bf(f0.z); h[3] = f2bf(f0.w);
            h[4] = f2bf(f1.x); h[5] = f2bf(f1.y); h[6] = f2bf(f1.z); h[7] = f2bf(f1.w);
            *(bf16x8*)(smA + slot * 16) = h;
        }
    }
    __syncthreads();   // only block-wide barrier before the epilogue

    f32x4 acc[4][4];
    #pragma unroll
    for (int rf = 0; rf < 4; ++rf)
        #pragma unroll
        for (int cf = 0; cf < 4; ++cf)
            acc[rf][cf] = (f32x4){0.f, 0.f, 0.f, 0.f};

    // wave w covers col-tiles cg = kc*32 + w*4 + cf
    const char* bp = (const char*)w1img + w * 4096 + lane * 16;

    bf16x8 bN[4];
    #pragma unroll
    for (int cf = 0; cf < 4; ++cf)
        bN[cf] = *(const bf16x8*)(bp + cf * 1024);

    #pragma unroll
    for (int kc = 0; kc < 8; ++kc) {
        bf16x8 bC[4];
        #pragma unroll
        for (int cf = 0; cf < 4; ++cf) bC[cf] = bN[cf];
        if (kc < 7) {
            #pragma unroll
            for (int cf = 0; cf < 4; ++cf)
                bN[cf] = *(const bf16x8*)(bp + (size_t)(kc + 1) * 32768 + cf * 1024);
        }
        bf16x8 aF[4];
        #pragma unroll
        for (int rf = 0; rf < 4; ++rf)
            aF[rf] = *(const bf16x8*)(smA + ((kc * 4 + rf) * 64 + lane) * 16);
        #pragma unroll
        for (int rf = 0; rf < 4; ++rf)
            #pragma unroll
            for (int cf = 0; cf < 4; ++cf)
                acc[rf][cf] = __builtin_amdgcn_mfma_f32_16x16x32_bf16(
                    aF[rf], bC[cf], acc[rf][cf], 0, 0, 0);
    }

    // ---- epilogue: selu + W21/W22 dots + 16-lane col reduce ----
    float cb[4], w21r[4], w22r[4];
    #pragma unroll
    for (int cf = 0; cf < 4; ++cf) {
        int col = w * 64 + cf * 16 + l15;
        cb[cf]   = cbias[b * 512 + col];
        w21r[cf] = fw21[col];
        w22r[cf] = fw22[col];
    }

    #pragma unroll
    for (int rf = 0; rf < 4; ++rf)
        #pragma unroll
        for (int q = 0; q < 4; ++q) {
            float m = 0.f, v = 0.f;
            #pragma unroll
            for (int cf = 0; cf < 4; ++cf) {
                float s_ = selu_f(acc[rf][cf][q] + cb[cf]);
                m += s_ * w21r[cf];
                v += s_ * w22r[cf];
            }
            #pragma unroll
            for (int d = 1; d < 16; d <<= 1) {
                m += __shfl_xor(m, d);
                v += __shfl_xor(v, d);
            }
            if (l15 == 0) {
                int row = rf * 16 + hi * 4 + q;
                redM[w][row] = m;
                redV[w][row] = v;
            }
        }

    __syncthreads();
    size_t obase = (size_t)b * 256 + s0v;
    if (tid < 64) {
        float s = 0.f;
        #pragma unroll
        for (int j = 0; j < 8; ++j) s += redM[j][tid];
        plm[obase + tid] = s;
    } else if (tid < 128) {
        int rr = tid - 64;
        float s = 0.f;
        #pragma unroll
        for (int j = 0; j < 8; ++j) s += redV[j][rr];
        plv[obase + rr] = s;
    }
}

// ---------------------------------------------------------------------------
// Kernel 4: per-b logsumexp over S=256 and final outputs (1 wave per b)
// ---------------------------------------------------------------------------
__global__ void __launch_bounds__(64) finalize_kernel(
    const float* __restrict__ plm, const float* __restrict__ plv,
    const float* __restrict__ w, const float* __restrict__ l,
    const float* __restrict__ b21p, const float* __restrict__ b22p,
    float* __restrict__ out)
{
    const int b = blockIdx.x;
    const int lane = threadIdx.x;
    const float b21 = b21p[0], b22 = b22p[0];

    float a1[4], a2[4];
    float m1 = -1e30f, m2 = -1e30f;
    #pragma unroll
    for (int i = 0; i < 4; ++i) {
        int s = i * 64 + lane;
        float lw = logf(w[b * 256 + s]);
        a1[i] = plm[b * 256 + s] + b21 + lw;
        a2[i] = plv[b * 256 + s] + b22 + 2.f * lw;
        m1 = fmaxf(m1, a1[i]);
        m2 = fmaxf(m2, a2[i]);
    }
    #pragma unroll
    for (int m = 1; m < 64; m <<= 1) {
        m1 = fmaxf(m1, __shfl_xor(m1, m));
        m2 = fmaxf(m2, __shfl_xor(m2, m));
    }
    float s1 = 0.f, s2 = 0.f;
    #pragma unroll
    for (int i = 0; i < 4; ++i) {
        s1 += expf(a1[i] - m1);
        s2 += expf(a2[i] - m2);
    }
    #pragma unroll
    for (int m = 1; m < 64; m <<= 1) {
        s1 += __shfl_xor(s1, m);
        s2 += __shfl_xor(s2, m);
    }
    if (lane == 0) {
        float lm_agg = m1 + logf(s1);
        float lv_agg = m2 + logf(s2);
        float logl = logf(l[b]);
        out[b]       = logl - lm_agg;
        out[512 + b] = logl - 3.f * lm_agg - lv_agg;
    }
}

extern "C" void kernel_launch(void* const* d_in, const int* in_sizes, int n_in,
                              void* d_out, int out_size, void* d_ws, size_t ws_size,
                              hipStream_t stream) {
    const float* rho     = (const float*)d_in[0];
    const float* c       = (const float*)d_in[1];
    const float* w       = (const float*)d_in[2];
    const float* l       = (const float*)d_in[3];
    // d_in[4] = roads (unused by the reference)
    const int*   lon_idx = (const int*)d_in[5];
    const int*   lat_idx = (const int*)d_in[6];
    const float* f2W1    = (const float*)d_in[7];
    const float* f2b1    = (const float*)d_in[8];
    const float* f2W2    = (const float*)d_in[9];
    const float* f2b2    = (const float*)d_in[10];
    const float* fW1     = (const float*)d_in[11];
    const float* fb1     = (const float*)d_in[12];
    const float* fW21    = (const float*)d_in[13];
    const float* fb21    = (const float*)d_in[14];
    const float* fW22    = (const float*)d_in[15];
    const float* fb22    = (const float*)d_in[16];
    float* out = (float*)d_out;

    char* ws = (char*)d_ws;
    float* cbias  = (float*)(ws);               // 1048576 B
    short* w1img  = (short*)(ws + 1048576);     //  262144 B
    float* plm    = (float*)(ws + 1310720);     //  524288 B
    float* plv    = (float*)(ws + 1835008);     //  524288 B

    prep_cbias_kernel<<<512, 512, 0, stream>>>(c, lat_idx, lon_idx,
                                               f2W1, f2b1, f2W2, f2b2,
                                               fW1, fb1, cbias);
    build_w1img_kernel<<<512, 256, 0, stream>>>(fW1, w1img);
    fused_gemm_kernel<<<2048, 512, 0, stream>>>(rho, w1img, cbias, fW21, fW22,
                                                plm, plv);
    finalize_kernel<<<512, 64, 0, stream>>>(plm, plv, w, l, fb21, fb22, out);
}

// Round 6
// 98.432 us; speedup vs baseline: 3.0945x; 1.0766x over previous
//
#include <hip/hip_runtime.h>
#include <hip/hip_bf16.h>

typedef short bf16x8 __attribute__((ext_vector_type(8)));
typedef float f32x4 __attribute__((ext_vector_type(4)));
typedef _Float16 half4 __attribute__((ext_vector_type(4)));

__device__ __forceinline__ short f2bf(float f) {
    union { float f; unsigned u; } v; v.f = f;
    unsigned r = (v.u + 0x7FFFu + ((v.u >> 16) & 1u)) >> 16;
    return (short)r;
}

__device__ __forceinline__ float selu_f(float x) {
    const float scale = 1.0507009873554805f;
    const float sa = 1.0507009873554805f * 1.6732632423543772f;
    return x > 0.f ? scale * x : sa * (__expf(x) - 1.f);
}

// ---------------------------------------------------------------------------
// Kernel 1: gather-mean + f2 MLP + cbias[b][col] = ctr_f32 @ W1[256:384,:] + b1
// ---------------------------------------------------------------------------
__global__ void __launch_bounds__(512) prep_cbias_kernel(
    const float* __restrict__ c, const int* __restrict__ lat_idx,
    const int* __restrict__ lon_idx,
    const float* __restrict__ f2W1, const float* __restrict__ f2b1,
    const float* __restrict__ f2W2, const float* __restrict__ f2b2,
    const float* __restrict__ fW1, const float* __restrict__ fb1,
    float* __restrict__ cbias)
{
    __shared__ int cells[64];
    __shared__ float ctraj[128];
    __shared__ float hbuf[256];
    __shared__ float ctrf[128];
    const int b = blockIdx.x;
    const int t = threadIdx.x;

    if (t < 64) cells[t] = lat_idx[b * 64 + t] * 17 + lon_idx[b * 64 + t];
    __syncthreads();

    if (t < 128) {
        float s = 0.f;
        #pragma unroll 8
        for (int j = 0; j < 64; ++j) s += c[t * 289 + cells[j]];
        ctraj[t] = s * (1.f / 64.f);
    }
    __syncthreads();

    if (t < 256) {
        float acc = f2b1[t];
        #pragma unroll 8
        for (int i = 0; i < 128; ++i) acc += ctraj[i] * f2W1[i * 256 + t];
        hbuf[t] = selu_f(acc);
    }
    __syncthreads();

    if (t < 128) {
        float acc = f2b2[t];
        #pragma unroll 8
        for (int i = 0; i < 256; ++i) acc += hbuf[i] * f2W2[i * 128 + t];
        ctrf[t] = acc;
    }
    __syncthreads();

    float acc = fb1[t];
    #pragma unroll 8
    for (int i = 0; i < 128; ++i) acc += ctrf[i] * fW1[(256 + i) * 512 + t];
    cbias[b * 512 + t] = acc;
}

// ---------------------------------------------------------------------------
// Kernel 2: W1[0:256,:] f32 -> fragment-major bf16 image.
// slot I = ((kc*32 + cg)*64 + lane)*8 + e holds
//   W1[kc*32 + (lane>>4)*8 + e][cg*16 + (lane&15)]
// ---------------------------------------------------------------------------
__global__ void __launch_bounds__(256) build_w1img_kernel(
    const float* __restrict__ fW1, short* __restrict__ img)
{
    int I = blockIdx.x * 256 + threadIdx.x;  // 0 .. 131071
    int e = I & 7;
    int lane = (I >> 3) & 63;
    int cg = (I >> 9) & 31;
    int kc = I >> 14;
    int col = cg * 16 + (lane & 15);
    int k = kc * 32 + ((lane >> 4) << 3) + e;
    img[I] = f2bf(fW1[k * 512 + col]);
}

// ---------------------------------------------------------------------------
// Kernel 2b: f16 B-table for the epilogue reduce-MFMA (16x16x16_f16 layout).
// chunk nc covers n = nc*16 .. nc*16+15; lane(hi,l15), e:
//   value = l15==0 ? W21[nc*16+hi*4+e] : l15==1 ? W22[...] : 0
// ---------------------------------------------------------------------------
__global__ void __launch_bounds__(256) build_wvec_kernel(
    const float* __restrict__ fW21, const float* __restrict__ fW22,
    _Float16* __restrict__ wvec)
{
    int I = blockIdx.x * 256 + threadIdx.x;   // 0..8191
    int e = I & 3;
    int lane = (I >> 2) & 63;
    int nc = I >> 8;
    int l15 = lane & 15, hi = lane >> 4;
    int n = nc * 16 + hi * 4 + e;
    float v = (l15 == 0) ? fW21[n] : (l15 == 1 ? fW22[n] : 0.f);
    wvec[I] = (_Float16)v;
}

// ---------------------------------------------------------------------------
// Kernel 3: fused GEMM (K=256, swapped operands -> C^T fragments) + selu +
// MFMA-based W21/W22 contraction (no shuffles).
// 2048 blocks x 512 threads (8 waves). Block tile 64 s-rows x 512 n-cols;
// wave w owns n in [w*64, w*64+64).
// ---------------------------------------------------------------------------
__global__ void __launch_bounds__(512, 4) fused_gemm_kernel(
    const float* __restrict__ rho, const short* __restrict__ w1img,
    const float* __restrict__ cbias, const _Float16* __restrict__ wvec,
    float* __restrict__ plm, float* __restrict__ plv)
{
    __shared__ __align__(16) char smA[32768];   // [kc8][rg4][lane64][16B]
    __shared__ float redM[8][64];
    __shared__ float redV[8][64];

    const int tid  = threadIdx.x;
    const int lane = tid & 63;
    const int w    = tid >> 6;      // n-wave 0..7
    const int l15  = lane & 15;
    const int hi   = lane >> 4;     // 0..3

    const int b   = blockIdx.x >> 2;
    const int s0v = (blockIdx.x & 3) << 6;

    // ---- stage A once: slot s = i*512 + tid, s = kc*256 + rg*64 + lane_s ----
    {
        const float* rbase = rho + (size_t)(b * 256 + s0v) * 256;
        #pragma unroll
        for (int i = 0; i < 4; ++i) {
            int slot = i * 512 + tid;
            int kc = slot >> 8;
            int rem = slot & 255;
            int rg = rem >> 6;
            int ls = rem & 63;
            int row = rg * 16 + (ls & 15);
            int k0 = kc * 32 + ((ls >> 4) << 3);
            const float* src = rbase + (size_t)row * 256 + k0;
            float4 f0 = *(const float4*)(src);
            float4 f1 = *(const float4*)(src + 4);
            bf16x8 h;
            h[0] = f2bf(f0.x); h[1] = f2bf(f0.y); h[2] = f2bf(f0.z); h[3] = f2bf(f0.w);
            h[4] = f2bf(f1.x); h[5] = f2bf(f1.y); h[6] = f2bf(f1.z); h[7] = f2bf(f1.w);
            *(bf16x8*)(smA + slot * 16) = h;
        }
    }
    __syncthreads();   // only block-wide barrier before the epilogue

    f32x4 acc[4][4];   // [nf][sf]: n = w*64+nf*16+hi*4+q, s = s0v+sf*16+l15
    #pragma unroll
    for (int nf = 0; nf < 4; ++nf)
        #pragma unroll
        for (int sf = 0; sf < 4; ++sf)
            acc[nf][sf] = (f32x4){0.f, 0.f, 0.f, 0.f};

    const char* bp = (const char*)w1img + w * 4096 + lane * 16;

    bf16x8 bN[4];
    #pragma unroll
    for (int nf = 0; nf < 4; ++nf)
        bN[nf] = *(const bf16x8*)(bp + nf * 1024);

    #pragma unroll
    for (int kc = 0; kc < 8; ++kc) {
        bf16x8 bC[4];
        #pragma unroll
        for (int nf = 0; nf < 4; ++nf) bC[nf] = bN[nf];
        if (kc < 7) {
            #pragma unroll
            for (int nf = 0; nf < 4; ++nf)
                bN[nf] = *(const bf16x8*)(bp + (size_t)(kc + 1) * 32768 + nf * 1024);
        }
        bf16x8 aF[4];
        #pragma unroll
        for (int sf = 0; sf < 4; ++sf)
            aF[sf] = *(const bf16x8*)(smA + ((kc * 4 + sf) * 64 + lane) * 16);
        // swapped: A = W1 frag (row=n), B = rho frag (col=s) -> C[n][s]
        #pragma unroll
        for (int nf = 0; nf < 4; ++nf)
            #pragma unroll
            for (int sf = 0; sf < 4; ++sf)
                acc[nf][sf] = __builtin_amdgcn_mfma_f32_16x16x32_bf16(
                    bC[nf], aF[sf], acc[nf][sf], 0, 0, 0);
    }

    // ---- epilogue: selu(acc + cbias) -> f16 A-frags -> 16x16x16 f16 MFMA
    //      against [w21|w22|0...] B-table. No cross-lane ops at all.
    f32x4 rd[4];
    #pragma unroll
    for (int sf = 0; sf < 4; ++sf) rd[sf] = (f32x4){0.f, 0.f, 0.f, 0.f};

    const int wn = w * 64;
    #pragma unroll
    for (int nf = 0; nf < 4; ++nf) {
        f32x4 cbf = *(const f32x4*)(cbias + b * 512 + wn + nf * 16 + hi * 4);
        half4 wv = *(const half4*)(wvec + (size_t)(w * 4 + nf) * 256 + lane * 4);
        #pragma unroll
        for (int sf = 0; sf < 4; ++sf) {
            half4 pa;
            #pragma unroll
            for (int q = 0; q < 4; ++q)
                pa[q] = (_Float16)selu_f(acc[nf][sf][q] + cbf[q]);
            rd[sf] = __builtin_amdgcn_mfma_f32_16x16x16f16(pa, wv, rd[sf], 0, 0, 0);
        }
    }

    // rd[sf]: col=l15 (0 -> m, 1 -> v), row s_local = sf*16 + hi*4 + q
    if (l15 == 0) {
        #pragma unroll
        for (int sf = 0; sf < 4; ++sf)
            *(f32x4*)&redM[w][sf * 16 + hi * 4] = rd[sf];
    } else if (l15 == 1) {
        #pragma unroll
        for (int sf = 0; sf < 4; ++sf)
            *(f32x4*)&redV[w][sf * 16 + hi * 4] = rd[sf];
    }

    __syncthreads();
    size_t obase = (size_t)b * 256 + s0v;
    if (tid < 64) {
        float s = 0.f;
        #pragma unroll
        for (int j = 0; j < 8; ++j) s += redM[j][tid];
        plm[obase + tid] = s;
    } else if (tid < 128) {
        int rr = tid - 64;
        float s = 0.f;
        #pragma unroll
        for (int j = 0; j < 8; ++j) s += redV[j][rr];
        plv[obase + rr] = s;
    }
}

// ---------------------------------------------------------------------------
// Kernel 4: per-b logsumexp over S=256 and final outputs (1 wave per b)
// ---------------------------------------------------------------------------
__global__ void __launch_bounds__(64) finalize_kernel(
    const float* __restrict__ plm, const float* __restrict__ plv,
    const float* __restrict__ w, const float* __restrict__ l,
    const float* __restrict__ b21p, const float* __restrict__ b22p,
    float* __restrict__ out)
{
    const int b = blockIdx.x;
    const int lane = threadIdx.x;
    const float b21 = b21p[0], b22 = b22p[0];

    float a1[4], a2[4];
    float m1 = -1e30f, m2 = -1e30f;
    #pragma unroll
    for (int i = 0; i < 4; ++i) {
        int s = i * 64 + lane;
        float lw = logf(w[b * 256 + s]);
        a1[i] = plm[b * 256 + s] + b21 + lw;
        a2[i] = plv[b * 256 + s] + b22 + 2.f * lw;
        m1 = fmaxf(m1, a1[i]);
        m2 = fmaxf(m2, a2[i]);
    }
    #pragma unroll
    for (int m = 1; m < 64; m <<= 1) {
        m1 = fmaxf(m1, __shfl_xor(m1, m));
        m2 = fmaxf(m2, __shfl_xor(m2, m));
    }
    float s1 = 0.f, s2 = 0.f;
    #pragma unroll
    for (int i = 0; i < 4; ++i) {
        s1 += expf(a1[i] - m1);
        s2 += expf(a2[i] - m2);
    }
    #pragma unroll
    for (int m = 1; m < 64; m <<= 1) {
        s1 += __shfl_xor(s1, m);
        s2 += __shfl_xor(s2, m);
    }
    if (lane == 0) {
        float lm_agg = m1 + logf(s1);
        float lv_agg = m2 + logf(s2);
        float logl = logf(l[b]);
        out[b]       = logl - lm_agg;
        out[512 + b] = logl - 3.f * lm_agg - lv_agg;
    }
}

extern "C" void kernel_launch(void* const* d_in, const int* in_sizes, int n_in,
                              void* d_out, int out_size, void* d_ws, size_t ws_size,
                              hipStream_t stream) {
    const float* rho     = (const float*)d_in[0];
    const float* c       = (const float*)d_in[1];
    const float* w       = (const float*)d_in[2];
    const float* l       = (const float*)d_in[3];
    // d_in[4] = roads (unused by the reference)
    const int*   lon_idx = (const int*)d_in[5];
    const int*   lat_idx = (const int*)d_in[6];
    const float* f2W1    = (const float*)d_in[7];
    const float* f2b1    = (const float*)d_in[8];
    const float* f2W2    = (const float*)d_in[9];
    const float* f2b2    = (const float*)d_in[10];
    const float* fW1     = (const float*)d_in[11];
    const float* fb1     = (const float*)d_in[12];
    const float* fW21    = (const float*)d_in[13];
    const float* fb21    = (const float*)d_in[14];
    const float* fW22    = (const float*)d_in[15];
    const float* fb22    = (const float*)d_in[16];
    float* out = (float*)d_out;

    char* ws = (char*)d_ws;
    float*     cbias = (float*)(ws);               // 1048576 B
    short*     w1img = (short*)(ws + 1048576);     //  262144 B
    float*     plm   = (float*)(ws + 1310720);     //  524288 B
    float*     plv   = (float*)(ws + 1835008);     //  524288 B
    _Float16*  wvec  = (_Float16*)(ws + 2359296);  //   16384 B

    prep_cbias_kernel<<<512, 512, 0, stream>>>(c, lat_idx, lon_idx,
                                               f2W1, f2b1, f2W2, f2b2,
                                               fW1, fb1, cbias);
    build_w1img_kernel<<<512, 256, 0, stream>>>(fW1, w1img);
    build_wvec_kernel<<<32, 256, 0, stream>>>(fW21, fW22, wvec);
    fused_gemm_kernel<<<2048, 512, 0, stream>>>(rho, w1img, cbias, wvec,
                                                plm, plv);
    finalize_kernel<<<512, 64, 0, stream>>>(plm, plv, w, l, fb21, fb22, out);
}